// Round 2
// baseline (76.047 us; speedup 1.0000x reference)
//
#include <hip/hip_runtime.h>

// BEV orthographic 3D Gaussian splatting, B=2, N=1024, D=32, H=W=200.
// Two kernels per launch:
//  1) prep_kernel (2 blocks, one per batch): per-gaussian conic/radius computed
//     ONCE, pruned (op>0.05, det>0, on-canvas circle) and compacted into d_ws
//     in input order (deterministic LDS-scan compaction). Also computes the
//     fused mean_count numerator.
//  2) render_kernel (25x25x2 blocks, 4 waves): each wave scans a contiguous
//     quarter of the compacted list (~2 groups of 64 vs 4 heavy groups before),
//     bbox-tests against its 8x8 tile, and composites survivors via
//     ballot-bit-scan + readlane broadcast (no barriers in the main loop).
// Per-gaussian math (u,v,A,B,C,o) is bit-identical to the previous version;
// eps-stop uses segment-local T with permanent stop -> strict superset of the
// reference's included set; added weight bounded ~1e-2 (absmax budget 19.44).
// Output: [bev (2,32,200,200) | mean_count scalar].

#define HH 200
#define WW 200
#define DD 32
#define NG 1024
#define BB 2
#define OUT_IMG (BB*DD*HH*WW)   // 2560000
#define NW 4                    // waves per render block
// ws layout: float4 entries[b][e][2]  (b<2, e<1024)  = 65536 B
//            then ints at 65536: cnt_entries[2], opcnt[2]
#define WS_ENT4(b,e) ((((b)<<10) + (e)) << 1)
#define WS_INT_OFF 16384        // in int units (65536/4)

__device__ __forceinline__ float rlane(float x, int l) {
    return __uint_as_float(__builtin_amdgcn_readlane(__float_as_uint(x), l));
}

__global__ __launch_bounds__(256) void prep_kernel(
    const float* __restrict__ means,   // (B, NG, 3)
    const float* __restrict__ cov,     // (B, NG, 6)
    const float* __restrict__ opac,    // (B, NG)
    float* __restrict__ ws)
{
    const int b    = blockIdx.x;
    const int tid  = threadIdx.x;
    const int lane = tid & 63;
    const int wid  = tid >> 6;
    __shared__ int wcnt[NW];
    float4* __restrict__ ws4 = (float4*)ws;
    int*    __restrict__ wsi = (int*)ws;

    int base = 0;   // uniform across block (all threads update identically)
    int opc  = 0;

    for (int r = 0; r < NG/256; ++r) {
        const int gl = r*256 + tid;              // gaussian idx within batch
        const int g  = b*NG + gl;
        const float o   = opac[g];
        opc += (o > 0.05f) ? 1 : 0;
        const float2 c01 = *(const float2*)(cov + (size_t)g*6);
        const float c3  = cov[(size_t)g*6 + 3];
        const float av = 4.f*c3    + 0.3f;       // image-x variance
        const float cv = 4.f*c01.x + 0.3f;       // image-y variance
        const float bv = 4.f*c01.y;
        const float det = av*cv - bv*bv;
        bool flag = false;
        float4 q0 = make_float4(0.f,0.f,0.f,0.f);
        float4 q1 = make_float4(0.f,0.f,0.f,0.f);
        if (o > 0.05f && det > 0.f) {
            const float u = -2.f*means[(size_t)g*3+1] + 100.f;
            const float v = -2.f*means[(size_t)g*3+0] + 100.f;
            const float qmax = 2.f*__logf(255.f*o);          // >0 since o>0.05
            const float htr = 0.5f*(av+cv), hdf = 0.5f*(av-cv);
            const float lmax = htr + sqrtf(hdf*hdf + bv*bv); // lmax(cov2D)
            const float rr = sqrtf(qmax*lmax) + 0.5f;        // tile-test radius
            // canvas cull: any tile test |u-cx|<=3.5+rr implies this (slack .01)
            if (fabsf(u - 99.5f) <= 99.51f + rr &&
                fabsf(v - 99.5f) <= 99.51f + rr) {
                const float inv = 1.f/det;
                q0 = make_float4(u, v, cv*inv, bv*inv);
                q1 = make_float4(av*inv, rr, o, __int_as_float(gl));
                flag = true;
            }
        }
        const unsigned long long mask = __ballot(flag);
        if (lane == 0) wcnt[wid] = (int)__popcll(mask);
        __syncthreads();
        const int pre = (wid>0 ? wcnt[0]:0) + (wid>1 ? wcnt[1]:0)
                      + (wid>2 ? wcnt[2]:0);
        if (flag) {                              // order-preserving compaction
            const int e = base + pre +
                (int)__popcll(mask & ((1ull << lane) - 1ull));
            ws4[WS_ENT4(b,e)    ] = q0;
            ws4[WS_ENT4(b,e) + 1] = q1;
        }
        base += wcnt[0]+wcnt[1]+wcnt[2]+wcnt[3];
        __syncthreads();                         // wcnt reused next round
    }

    // block-reduce opc (fused mean_count numerator)
#pragma unroll
    for (int off = 32; off > 0; off >>= 1) opc += __shfl_down(opc, off, 64);
    if (lane == 0) wcnt[wid] = opc;
    __syncthreads();
    if (tid == 0) {
        wsi[WS_INT_OFF + b]     = base;                          // entry count
        wsi[WS_INT_OFF + 2 + b] = wcnt[0]+wcnt[1]+wcnt[2]+wcnt[3];
    }
}

__global__ __launch_bounds__(64*NW, 4) void render_kernel(
    const float* __restrict__ feats,   // (B, NG, DD)
    const float* __restrict__ ws,
    float* __restrict__ out)
{
    __shared__ float4 simg[NW][64][8];   // swizzled ch4 slot = (c4+px)&7
    __shared__ float sT[NW][64];

    const int b    = blockIdx.z;
    const int tid  = threadIdx.x;
    const int lane = tid & 63;
    const int wid  = tid >> 6;
    const float pxf = (float)(blockIdx.x*8 + (lane & 7));
    const float pyf = (float)(blockIdx.y*8 + (lane >> 3));
    const float cx  = blockIdx.x*8 + 3.5f;
    const float cy  = blockIdx.y*8 + 3.5f;

    const float4* __restrict__ ws4 = (const float4*)ws;
    const int*    __restrict__ wsi = (const int*)ws;
    const float*  __restrict__ featsB = feats + (size_t)b * NG * DD;

    const int cnt = wsi[WS_INT_OFF + b];
    const int Q   = (cnt + 3) >> 2;              // per-wave contiguous range
    const int e0w = wid * Q;
    const int e1w = min(e0w + Q, cnt);

    float4 acc[8];
#pragma unroll
    for (int j = 0; j < 8; ++j) acc[j] = make_float4(0.f,0.f,0.f,0.f);
    float T = 1.f;
    bool alive = true;

    for (int e0 = e0w; e0 < e1w && alive; e0 += 64) {
        const int e = e0 + lane;                 // may read past e1w: gated
        const float4 q0 = ws4[WS_ENT4(b,e)    ];
        const float4 q1 = ws4[WS_ENT4(b,e) + 1];
        const bool flag = (e < e1w) &&
            fabsf(q0.x - cx) <= 3.5f + q1.y &&
            fabsf(q0.y - cy) <= 3.5f + q1.y;
        unsigned long long mm = __ballot(flag);  // bit order == input order
        while (mm) {
            const int i = (int)__builtin_ctzll(mm);
            mm &= mm - 1ull;
            const float dx = rlane(q0.x, i) - pxf;
            const float dy = rlane(q0.y, i) - pyf;
            const float Ai = rlane(q0.z, i);
            const float Bi = rlane(q0.w, i);
            const float Ci = rlane(q1.x, i);
            const float pw = fmaf(Bi, dx*dy, -0.5f*(Ai*dx*dx + Ci*dy*dy));
            if (pw > 0.f) continue;                    // reference mask
            const float oi = rlane(q1.z, i);
            const float alpha = fminf(0.99f, oi * __expf(pw));
            if (alpha < (1.f/255.f)) continue;         // exact check
            const float om = 1.f - alpha;
            if (T * om < 1e-4f) { alive = false; break; }  // eps-stop
            const float w = alpha * T;
            const int gi = __builtin_amdgcn_readlane(__float_as_int(q1.w), i);
            const float4* __restrict__ col =           // wave-uniform addr
                (const float4*)(featsB + (size_t)gi * DD);
#pragma unroll
            for (int j = 0; j < 8; ++j) {
                const float4 c4 = col[j];
                acc[j].x = fmaf(w, c4.x, acc[j].x);
                acc[j].y = fmaf(w, c4.y, acc[j].y);
                acc[j].z = fmaf(w, c4.z, acc[j].z);
                acc[j].w = fmaf(w, c4.w, acc[j].w);
            }
            T *= om;
        }
    }

    // ---- cross-wave combine: img = sum_s prefixT_s * img_s
    sT[wid][lane] = T;
#pragma unroll
    for (int j = 0; j < 8; ++j)
        simg[wid][lane][(j + lane) & 7] = acc[j];        // bank-swizzled
    __syncthreads();

    {
        const int p   = tid & 63;                        // pixel within tile
        const int grp = tid >> 6;                        // channel-quad pair
        const float t0 = sT[0][p], t1 = sT[1][p], t2 = sT[2][p];
        const float pf1 = t0, pf2 = t0*t1, pf3 = pf2*t2;
        const int ppx = blockIdx.x*8 + (p & 7);
        const int ppy = blockIdx.y*8 + (p >> 3);
        const size_t base = (size_t)b * DD * (HH*WW) + (size_t)ppy * WW + ppx;
#pragma unroll
        for (int q = 0; q < 2; ++q) {
            const int c4 = grp*2 + q;
            const int slot = (c4 + p) & 7;
            const float4 r0 = simg[0][p][slot];
            const float4 r1 = simg[1][p][slot];
            const float4 r2 = simg[2][p][slot];
            const float4 r3 = simg[3][p][slot];
            float4 ov;
            ov.x = fmaf(pf3, r3.x, fmaf(pf2, r2.x, fmaf(pf1, r1.x, r0.x)));
            ov.y = fmaf(pf3, r3.y, fmaf(pf2, r2.y, fmaf(pf1, r1.y, r0.y)));
            ov.z = fmaf(pf3, r3.z, fmaf(pf2, r2.z, fmaf(pf1, r1.z, r0.z)));
            ov.w = fmaf(pf3, r3.w, fmaf(pf2, r2.w, fmaf(pf1, r1.w, r0.w)));
            out[base + (size_t)(c4*4+0)*(HH*WW)] = ov.x;
            out[base + (size_t)(c4*4+1)*(HH*WW)] = ov.y;
            out[base + (size_t)(c4*4+2)*(HH*WW)] = ov.z;
            out[base + (size_t)(c4*4+3)*(HH*WW)] = ov.w;
        }
    }

    // ---- fused mean_count (numerators precomputed by prep_kernel)
    if (blockIdx.x == 0 && blockIdx.y == 0 && b == 0 && tid == 0)
        out[OUT_IMG] = (float)(wsi[WS_INT_OFF+2] + wsi[WS_INT_OFF+3]) * 0.5f;
}

extern "C" void kernel_launch(void* const* d_in, const int* in_sizes, int n_in,
                              void* d_out, int out_size, void* d_ws, size_t ws_size,
                              hipStream_t stream) {
    const float* feats = (const float*)d_in[0];  // features (B,N,D)
    const float* means = (const float*)d_in[1];  // means3D  (B,N,3)
    const float* cvr   = (const float*)d_in[2];  // cov3D    (B,N,6)
    const float* opc   = (const float*)d_in[3];  // opacities(B,N,1)
    float* out = (float*)d_out;
    float* ws  = (float*)d_ws;

    prep_kernel<<<dim3(BB), dim3(256), 0, stream>>>(means, cvr, opc, ws);
    render_kernel<<<dim3(WW/8, HH/8, BB), dim3(64*NW), 0, stream>>>(
        feats, ws, out);
}